// Round 10
// baseline (183.954 us; speedup 1.0000x reference)
//
#include <hip/hip_runtime.h>
#include <hip/hip_bf16.h>
#include <math.h>

#define BB 2
#define HH 16
#define LL 1024
#define DD 64
#define EE 1024
#define NEGV -1e20f

typedef __attribute__((ext_vector_type(8))) short bf16x8;
typedef __attribute__((ext_vector_type(4))) float f32x4;

__device__ __forceinline__ float bf2f(__hip_bfloat16 x){ return __bfloat162float(x); }
__device__ __forceinline__ float gelu_erf(float x){
    return 0.5f * x * (1.0f + erff(x * 0.70710678118654752f));
}
__device__ __forceinline__ float ldx(const void* p, size_t i, int f32){
    return f32 ? ((const float*)p)[i] : bf2f(((const __hip_bfloat16*)p)[i]);
}
__device__ __forceinline__ short f2bs(float x){
    __hip_bfloat16 h = __float2bfloat16(x);
    return *(short*)&h;
}
__device__ __forceinline__ float bs2f(unsigned short u){
    return __uint_as_float(((unsigned)u) << 16);
}
__device__ __forceinline__ bf16x8 ld8b(const void* p, size_t i, int f32){
    bf16x8 r;
    if (f32){
        const float4* f = (const float4*)((const float*)p + i);
        float4 a = f[0], b = f[1];
        r[0]=f2bs(a.x); r[1]=f2bs(a.y); r[2]=f2bs(a.z); r[3]=f2bs(a.w);
        r[4]=f2bs(b.x); r[5]=f2bs(b.y); r[6]=f2bs(b.z); r[7]=f2bs(b.w);
    } else {
        r = *(const bf16x8*)((const __hip_bfloat16*)p + i);
    }
    return r;
}
__device__ __forceinline__ float redsum16(float x){
    x += __shfl_xor(x, 1); x += __shfl_xor(x, 2);
    x += __shfl_xor(x, 4); x += __shfl_xor(x, 8);
    return x;
}
// detect f32 (1) vs bf16 (0) from bits 14..7 of first 64 words
__device__ __forceinline__ int detect_f32(const unsigned int* p){
    int inband = 0;
    #pragma unroll 1
    for (int w = 0; w < 64; ++w){
        unsigned int e0 = (p[w] >> 7) & 0xFFu;
        if (e0 >= 0x60u && e0 <= 0x8Eu) inband++;
    }
    return (inband >= 48) ? 0 : 1;
}
// ber_mask storage encoding: 0=u8, 1=i32, 2=bf16, 3=f32
__device__ __forceinline__ int ber_code(const unsigned char* r){
    bool has_big = false, odd1 = false, nz_off = false;
    #pragma unroll 1
    for (int j = 0; j < 128; ++j){
        unsigned char c = r[j];
        if (c > 1) has_big = true;
        if ((j & 3) == 1 && c) odd1 = true;
        if ((j & 3) != 0 && c) nz_off = true;
    }
    if (has_big) return odd1 ? 2 : 3;
    return nz_off ? 0 : 1;
}
__device__ __forceinline__ float ber_val(const unsigned char* r, int i, int code){
    switch (code){
        case 0:  return r[i] ? 1.f : 0.f;
        case 1:  return (((const int*)r)[i] != 0) ? 1.f : 0.f;
        case 2:  return (((const unsigned short*)r)[i] != 0) ? 1.f : 0.f;
        default: return (((const float*)r)[i] != 0.f) ? 1.f : 0.f;
    }
}

// ---------------------------------------------------------------------------
// kA: role-split. blk<512: depthwise conv+bias+residual -> qbf (pre-BN bf16),
//     BN partial sums (atomic-free); blk0 also publishes dtype flag to ws.
//     blk>=512: key-softmax partial denoms (max-free) + berf decode.
// ---------------------------------------------------------------------------
__global__ __launch_bounds__(256, 2) void kA(const void* __restrict__ query,
                                             const void* __restrict__ conv_w,
                                             const void* __restrict__ conv_b,
                                             const void* __restrict__ keys,
                                             const unsigned char* __restrict__ ber_raw,
                                             float* __restrict__ statsP,
                                             float* __restrict__ Sp,
                                             float* __restrict__ berf,
                                             int* __restrict__ wsflag,
                                             __hip_bfloat16* __restrict__ qbf){
    __shared__ float tile[66][67];
    __shared__ float r1[256], r2[256];
    __shared__ float ss[4][64];
    __shared__ int sflag, sdet;
    int blk = blockIdx.x, t = threadIdx.x;
    if (blk < 512){
        // ---------------- conv role ----------------
        if (t == 0){
            sflag = detect_f32((const unsigned int*)query);
            if (blk == 0) wsflag[0] = sflag;
        }
        int lt = blk & 15, h = (blk >> 4) & 15, b = blk >> 8;
        int bh = b * HH + h;
        int l0 = lt * 64;
        if (t < 66){ tile[t][0] = 0.f; tile[t][65] = 0.f; }
        __syncthreads();
        const int f32 = sflag;
        for (int i = t; i < 66 * 64; i += 256){
            int r = i >> 6, d = i & 63;
            int l = l0 - 1 + r;
            tile[r][d + 1] = (l >= 0 && l < LL)
                           ? ldx(query, ((size_t)b * LL + l) * EE + h * 64 + d, f32) : 0.f;
        }
        __syncthreads();
        float w9[9];
        #pragma unroll
        for (int i = 0; i < 9; ++i) w9[i] = ldx(conv_w, h * 9 + i, f32);
        float cb = ldx(conv_b, h, f32);
        int l = t & 63, db = t >> 6, d0 = db * 16;
        float s1 = 0.f, s2 = 0.f;
        unsigned short ob[16];
        #pragma unroll
        for (int jj = 0; jj < 16; ++jj){
            int d = d0 + jj;
            float acc = cb + tile[l + 1][d + 1];
            #pragma unroll
            for (int di = 0; di < 3; ++di)
                #pragma unroll
                for (int dj = 0; dj < 3; ++dj)
                    acc += w9[di * 3 + dj] * tile[l + di][d + dj];
            s1 += acc; s2 += acc * acc;
            ob[jj] = (unsigned short)f2bs(acc);
        }
        __hip_bfloat16* orow = qbf + ((size_t)bh * LL + l0 + l) * DD + d0;
        #pragma unroll
        for (int g = 0; g < 4; ++g){
            ushort4 u; u.x = ob[g*4]; u.y = ob[g*4+1]; u.z = ob[g*4+2]; u.w = ob[g*4+3];
            *(ushort4*)(orow + g * 4) = u;
        }
        r1[t] = s1; r2[t] = s2;
        __syncthreads();
        for (int s = 128; s > 0; s >>= 1){
            if (t < s){ r1[t] += r1[t + s]; r2[t] += r2[t + s]; }
            __syncthreads();
        }
        if (t == 0){
            statsP[h * 32 + b * 16 + lt] = r1[0];
            statsP[512 + h * 32 + b * 16 + lt] = r2[0];
        }
    } else {
        // ---------------- key-softmax role ----------------
        int blk2 = blk - 512;
        if (t == 0){ sflag = detect_f32((const unsigned int*)keys); sdet = ber_code(ber_raw); }
        __syncthreads();
        const int f32 = sflag, code = sdet;
        int ch = blk2 & 15, h = (blk2 >> 4) & 15, b = blk2 >> 8;
        int ex = t & 63, ly = t >> 6;
        int e = h * 64 + ex;
        float s = 0.f;
        #pragma unroll 4
        for (int l = ch * 64 + ly; l < ch * 64 + 64; l += 4){
            float keep = ber_val(ber_raw, b * LL + l, code);
            float x = (keep != 0.f) ? ldx(keys, ((size_t)b * LL + l) * EE + e, f32) : NEGV;
            s += __expf(x);
        }
        ss[ly][ex] = s;
        __syncthreads();
        if (ly == 0)
            Sp[(b * 16 + ch) * EE + e] = ss[0][ex] + ss[1][ex] + ss[2][ex] + ss[3][ex];
        if (h == 0 && t < 64)
            berf[b * LL + ch * 64 + t] = ber_val(ber_raw, b * LL + ch * 64 + t, code);
    }
}

// ---------------------------------------------------------------------------
// kC: role-split. blk<1024: fused elementwise finalize: q = gelu(bn(qbf))
//     in-place (BN coef via shfl-reduce from statsP) and
//     kb = gelu(exp(keys)*Sinv) (Sinv reduced locally from Sp).
//     blk>=1024: MFMA value projection -> vbT[bh][e][l].
// ---------------------------------------------------------------------------
__global__ __launch_bounds__(256, 2) void kC(const void* __restrict__ keys,
                                             const void* __restrict__ values,
                                             const void* __restrict__ w_v,
                                             const void* __restrict__ bn_g,
                                             const void* __restrict__ bn_b,
                                             const float* __restrict__ statsP,
                                             const float* __restrict__ Sp,
                                             const float* __restrict__ berf,
                                             const int* __restrict__ wsflag,
                                             __hip_bfloat16* __restrict__ qbf,
                                             __hip_bfloat16* __restrict__ kb,
                                             __hip_bfloat16* __restrict__ vbT){
    __shared__ float sinv_s[64];
    __shared__ float sc[2];
    int blk = blockIdx.x, t = threadIdx.x;
    const int f32 = wsflag[0];
    if (blk < 1024){
        // ---------------- elementwise finalize role ----------------
        int idx = blk * 256 + t;
        int i8 = idx * 8;
        int d0 = i8 & 63, l = (i8 >> 6) & 1023, h = (i8 >> 16) & 15, b = i8 >> 20;
        if (t < 64){
            // shfl-parallel BN stat reduction (lanes 0..31 carry data)
            float s1p = (t < 32) ? statsP[h * 32 + t] : 0.f;
            float s2p = (t < 32) ? statsP[512 + h * 32 + t] : 0.f;
            #pragma unroll
            for (int off = 16; off > 0; off >>= 1){
                s1p += __shfl_xor(s1p, off);
                s2p += __shfl_xor(s2p, off);
            }
            if (t == 0){
                const float N = (float)(BB * LL * DD);
                float mean = s1p / N;
                float var  = fmaxf(s2p / N - mean * mean, 0.f);
                float a = ldx(bn_g, h, f32) * rsqrtf(var + 1e-5f);
                sc[0] = a;
                sc[1] = ldx(bn_b, h, f32) - mean * a;
            }
            int e = h * 64 + t;
            float S = 0.f;
            #pragma unroll
            for (int ch = 0; ch < 16; ++ch) S += Sp[(b * 16 + ch) * EE + e];
            sinv_s[t] = 1.f / S;
        }
        __syncthreads();
        float bna = sc[0], bnc = sc[1];
        // q path (qbf bf16 in-place)
        uint4 qr = *(uint4*)(qbf + i8);
        unsigned short* qs = (unsigned short*)&qr;
        uint4 qw;
        unsigned short* qws = (unsigned short*)&qw;
        #pragma unroll
        for (int j = 0; j < 8; ++j)
            qws[j] = (unsigned short)f2bs(gelu_erf(bs2f(qs[j]) * bna + bnc));
        *(uint4*)(qbf + i8) = qw;
        // k path
        size_t kbase = ((size_t)b * LL + l) * EE + h * 64 + d0;
        float kv[8];
        if (f32){
            const float4* kp = (const float4*)((const float*)keys + kbase);
            float4 a = kp[0], c = kp[1];
            kv[0]=a.x; kv[1]=a.y; kv[2]=a.z; kv[3]=a.w;
            kv[4]=c.x; kv[5]=c.y; kv[6]=c.z; kv[7]=c.w;
        } else {
            uint4 kr = *(const uint4*)((const __hip_bfloat16*)keys + kbase);
            unsigned short* ks = (unsigned short*)&kr;
            #pragma unroll
            for (int j = 0; j < 8; ++j) kv[j] = bs2f(ks[j]);
        }
        float keep = berf[b * LL + l];
        uint4 kw;
        unsigned short* kws = (unsigned short*)&kw;
        #pragma unroll
        for (int j = 0; j < 8; ++j){
            float km = (keep != 0.f) ? kv[j] : NEGV;
            float p = __expf(km) * sinv_s[d0 + j];
            kws[j] = (unsigned short)f2bs(gelu_erf(p));
        }
        *(uint4*)(kb + i8) = kw;
    } else {
        // ---------------- MFMA v-projection role ----------------
        int blk2 = blk - 1024;
        int lt = blk2 & 15, bh = blk2 >> 4;
        int h = bh & 15, b = bh >> 4;
        int w = t >> 6, lane = t & 63;
        int lid = lane & 15, quad = lane >> 4;
        int l = lt * 64 + w * 16 + lid;
        bf16x8 av[2];
        #pragma unroll
        for (int ck = 0; ck < 2; ++ck)
            av[ck] = ld8b(values, ((size_t)b * LL + l) * EE + h * 64 + ck * 32 + quad * 8, f32);
        f32x4 Dv[4];
        #pragma unroll
        for (int et = 0; et < 4; ++et){
            Dv[et] = (f32x4){0.f, 0.f, 0.f, 0.f};
            #pragma unroll
            for (int ck = 0; ck < 2; ++ck){
                bf16x8 bw = ld8b(w_v, (size_t)(et * 16 + lid) * 64 + ck * 32 + quad * 8, f32);
                Dv[et] = __builtin_amdgcn_mfma_f32_16x16x32_bf16(av[ck], bw, Dv[et], 0, 0, 0);
            }
        }
        #pragma unroll
        for (int et = 0; et < 4; ++et){
            ushort4 u;
            u.x = (unsigned short)f2bs(Dv[et][0]);
            u.y = (unsigned short)f2bs(Dv[et][1]);
            u.z = (unsigned short)f2bs(Dv[et][2]);
            u.w = (unsigned short)f2bs(Dv[et][3]);
            *(ushort4*)(vbT + ((size_t)bh * DD + et * 16 + lid) * LL + lt * 64 + w * 16 + quad * 4) = u;
        }
    }
}

// ---------------------------------------------------------------------------
// kD: barrier-free MFMA flash attention, 4-way wave split for full occupancy.
// 2048 blocks x 256 thr (4 waves) = 8192 waves = 32 waves/CU.
// Block = (qt: 16 q-rows, bh). Wave w: pair pr=w>>1 takes half the causal
// tile range (additive max-free softmax => exact partial-O sum), kh=w&1
// takes k-cols kh*32..kh*32+31 of each 64-tile.
// K/V fragments load DIRECTLY from global (L2-resident via blk&31 XCD
// round-robin) -- no k-loop barriers. P round-trips per-wave LDS only.
// Epilogue: waves 1-3 dump O to LDS, wave 0 combines + LayerNorm, then each
// wave computes one 16-col W_o tile. LDS ~20 KB -> 8 blocks/CU.
// ---------------------------------------------------------------------------
__global__ __launch_bounds__(256, 8) void kD(const __hip_bfloat16* __restrict__ qbf,
                                             const __hip_bfloat16* __restrict__ kb,
                                             const __hip_bfloat16* __restrict__ vbT,
                                             const void* __restrict__ w_o,
                                             const void* __restrict__ b_o,
                                             const void* __restrict__ ln_g,
                                             const void* __restrict__ ln_b,
                                             const int* __restrict__ wsflag,
                                             void* __restrict__ out){
    __shared__ __align__(16) __hip_bfloat16 Pl[4][16][40];  // per-wave P (16x32)
    __shared__ __align__(16) float Ol[3][16][66];           // waves 1-3 partial O
    __shared__ __align__(16) __hip_bfloat16 onb[16][72];    // LN'd rows (A-frags)
    int blk = blockIdx.x;
    int qt = 63 - (blk >> 5);         // 16-row q tile; LPT (heavy first)
    int bh = blk & 31;                // b*16+h ; same-bh blocks share an XCD
    int h = bh & 15, b = bh >> 4;
    int t = threadIdx.x;
    int w = t >> 6, lane = t & 63;
    int lid = lane & 15, quad = lane >> 4;
    int kh = w & 1, pr = w >> 1;
    const int f32o = wsflag[0];

    // Q A-frags (finalized q from kC)
    int qrow = qt * 16 + lid;
    bf16x8 qf[2];
    #pragma unroll
    for (int ck = 0; ck < 2; ++ck)
        qf[ck] = *(const bf16x8*)(qbf + ((size_t)bh * LL + qrow) * DD + ck * 32 + quad * 8);

    const __hip_bfloat16* kbb = kb + (size_t)bh * LL * DD;
    const __hip_bfloat16* vbb = vbT + (size_t)bh * DD * LL;
    f32x4 O[4];
    #pragma unroll
    for (int nt = 0; nt < 4; ++nt) O[nt] = (f32x4){0.f, 0.f, 0.f, 0.f};
    const int qlane = qt * 16 + quad * 4;      // + r = this lane's q rows
    const int nkt = (qt >> 2) + 1;             // 64-k tiles covering causal range
    const int n0 = (nkt + 1) >> 1;             // pair 0: tiles [0,n0), pair 1: rest
    const int tbeg = pr ? n0 : 0;
    const int tend = pr ? nkt : n0;

    for (int kt0 = tbeg; kt0 < tend; ++kt0){
        int kw0 = kt0 * 64 + kh * 32;          // this wave's 32 k-cols
        // S = Q K^T for 16q x 32k (2 n-tiles); K B-frags straight from global
        f32x4 S[2];
        #pragma unroll
        for (int nt2 = 0; nt2 < 2; ++nt2){
            S[nt2] = (f32x4){0.f, 0.f, 0.f, 0.f};
            const __hip_bfloat16* krow = kbb + (size_t)(kw0 + nt2 * 16 + lid) * DD;
            #pragma unroll
            for (int ck = 0; ck < 2; ++ck){
                bf16x8 bk = *(const bf16x8*)(krow + ck * 32 + quad * 8);
                S[nt2] = __builtin_amdgcn_mfma_f32_16x16x32_bf16(qf[ck], bk, S[nt2], 0, 0, 0);
            }
        }
        // p = exp(gelu(s)/32) causal-masked -> per-wave LDS (C -> A-frag layout)
        // gelu(s)/32 = t*sigmoid(54.4638*t) with t = s/32
        #pragma unroll
        for (int nt2 = 0; nt2 < 2; ++nt2){
            int kcol = kw0 + nt2 * 16 + lid;
            #pragma unroll
            for (int r = 0; r < 4; ++r){
                float tv = S[nt2][r] * 0.03125f;
                float e = __expf(-54.4638f * tv);
                float x = tv * __builtin_amdgcn_rcpf(1.0f + e);
                float p = __expf(x);
                p = (kcol <= qlane + r) ? p : 0.f;
                Pl[w][quad * 4 + r][nt2 * 16 + lid] = __float2bfloat16(p);
            }
        }
        bf16x8 pa = *(const bf16x8*)&Pl[w][lid][quad * 8];   // same-wave RAW
        // O += P V ; V B-frags straight from global (vbT is k-contiguous)
        #pragma unroll
        for (int nt = 0; nt < 4; ++nt){
            bf16x8 bv = *(const bf16x8*)(vbb + (size_t)(nt * 16 + lid) * LL + kw0 + quad * 8);
            O[nt] = __builtin_amdgcn_mfma_f32_16x16x32_bf16(pa, bv, O[nt], 0, 0, 0);
        }
    }

    // ---- combine the four partial accumulators
    if (w > 0){
        #pragma unroll
        for (int nt = 0; nt < 4; ++nt)
            #pragma unroll
            for (int r = 0; r < 4; ++r)
                Ol[w - 1][quad * 4 + r][nt * 16 + lid] = O[nt][r];
    }
    __syncthreads();
    if (w == 0){
        #pragma unroll
        for (int j = 0; j < 3; ++j)
            #pragma unroll
            for (int nt = 0; nt < 4; ++nt)
                #pragma unroll
                for (int r = 0; r < 4; ++r)
                    O[nt][r] += Ol[j][quad * 4 + r][nt * 16 + lid];
        // LayerNorm over d (scale-invariant: unnormalized O is fine)
        float lng_v[4], lnb_v[4];
        #pragma unroll
        for (int nt = 0; nt < 4; ++nt){
            lng_v[nt] = ldx(ln_g, nt * 16 + lid, f32o);
            lnb_v[nt] = ldx(ln_b, nt * 16 + lid, f32o);
        }
        #pragma unroll
        for (int r = 0; r < 4; ++r){
            float s = O[0][r] + O[1][r] + O[2][r] + O[3][r];
            s = redsum16(s);
            float mu = s * (1.f / 64.f);
            float vs = 0.f;
            #pragma unroll
            for (int nt = 0; nt < 4; ++nt){ float d2 = O[nt][r] - mu; vs += d2 * d2; }
            vs = redsum16(vs);
            float iv = rsqrtf(vs * (1.f / 64.f) + 1e-5f);
            #pragma unroll
            for (int nt = 0; nt < 4; ++nt){
                float on = (O[nt][r] - mu) * iv * lng_v[nt] + lnb_v[nt];
                onb[quad * 4 + r][nt * 16 + lid] = __float2bfloat16(on);
            }
        }
    }
    __syncthreads();
    // ---- W_o epilogue: each wave computes one 16-col e-tile (et = w)
    bf16x8 oa0 = *(const bf16x8*)&onb[lid][quad * 8];
    bf16x8 oa1 = *(const bf16x8*)&onb[lid][32 + quad * 8];
    {
        int et = w;
        float bo = ldx(b_o, et * 16 + lid, f32o);
        f32x4 R = (f32x4){bo, bo, bo, bo};
        bf16x8 bw0 = ld8b(w_o, (size_t)(et * 16 + lid) * 64 + quad * 8, f32o);
        bf16x8 bw1 = ld8b(w_o, (size_t)(et * 16 + lid) * 64 + 32 + quad * 8, f32o);
        R = __builtin_amdgcn_mfma_f32_16x16x32_bf16(oa0, bw0, R, 0, 0, 0);
        R = __builtin_amdgcn_mfma_f32_16x16x32_bf16(oa1, bw1, R, 0, 0, 0);
        #pragma unroll
        for (int r = 0; r < 4; ++r){
            size_t oidx = ((size_t)b * LL + qlane + r) * EE + h * 64 + et * 16 + lid;
            if (f32o) ((float*)out)[oidx] = R[r];
            else      ((__hip_bfloat16*)out)[oidx] = __float2bfloat16(R[r]);
        }
    }
}

// ---------------------------------------------------------------------------
extern "C" void kernel_launch(void* const* d_in, const int* in_sizes, int n_in,
                              void* d_out, int out_size, void* d_ws, size_t ws_size,
                              hipStream_t stream){
    int iq=-1, ik=-1, iv=-1, iber=-1, icw=-1, icb=-1, ibg=-1, ibb=-1,
        iwv=-1, ilg=-1, ilb=-1, iwo=-1, ibo=-1;
    int nbig=0, n16=0, n4096=0, n64=0;
    for (int i = 0; i < n_in; ++i){
        int s = in_sizes[i];
        if (s == BB*LL*EE){ if (nbig==0) iq=i; else if (nbig==1) ik=i; else if (nbig==2) iv=i; nbig++; }
        else if (s == BB*LL) iber = i;
        else if (s == HH*9)  icw = i;
        else if (s == HH){ if (n16==0) icb=i; else if (n16==1) ibg=i; else ibb=i; n16++; }
        else if (s == DD*DD){ if (n4096==0) iwv=i; else iwo=i; n4096++; }
        else if (s == DD){ if (n64==0) ilg=i; else if (n64==1) ilb=i; else ibo=i; n64++; }
    }
    if (iq<0||ik<0||iv<0||iber<0||icw<0||icb<0||ibg<0||ibb<0||iwv<0||ilg<0||ilb<0||iwo<0||ibo<0){
        iq=0; ik=1; iv=2; iber=5; icw=6; icb=7; ibg=8; ibb=9; iwv=10; ilg=11; ilb=12; iwo=13; ibo=14;
    }

    const size_t NEL = (size_t)BB * HH * LL * DD;   // 2M
    __hip_bfloat16* qbf = (__hip_bfloat16*)d_ws;    // 4 MB
    __hip_bfloat16* kbw = qbf + NEL;                // 4 MB
    __hip_bfloat16* vbT = kbw + NEL;                // 4 MB
    float* f     = (float*)(vbT + NEL);
    float* berf  = f;              // 2048
    float* statsP= f + 2048;       // 1024
    float* Sp    = f + 3072;       // 32768
    int*   wsflag= (int*)(f + 35840);

    hipLaunchKernelGGL(kA, dim3(1024), dim3(256), 0, stream,
                       d_in[iq], d_in[icw], d_in[icb], d_in[ik],
                       (const unsigned char*)d_in[iber], statsP, Sp, berf, wsflag, qbf);
    hipLaunchKernelGGL(kC, dim3(1536), dim3(256), 0, stream,
                       d_in[ik], d_in[iv], d_in[iwv], d_in[ibg], d_in[ibb],
                       statsP, Sp, berf, wsflag, qbf, kbw, vbT);
    hipLaunchKernelGGL(kD, dim3(2048), dim3(256), 0, stream,
                       qbf, kbw, vbT, d_in[iwo], d_in[ibo], d_in[ilg], d_in[ilb],
                       wsflag, d_out);
}

// Round 11
// 182.494 us; speedup vs baseline: 1.0080x; 1.0080x over previous
//
#include <hip/hip_runtime.h>
#include <hip/hip_bf16.h>
#include <math.h>

#define BB 2
#define HH 16
#define LL 1024
#define DD 64
#define EE 1024
#define NEGV -1e20f

typedef __attribute__((ext_vector_type(8))) short bf16x8;
typedef __attribute__((ext_vector_type(4))) float f32x4;

__device__ __forceinline__ float bf2f(__hip_bfloat16 x){ return __bfloat162float(x); }
__device__ __forceinline__ float gelu_erf(float x){
    return 0.5f * x * (1.0f + erff(x * 0.70710678118654752f));
}
// cheap gelu for score path only (|err|<=0.01, scaled by 1/32 afterwards)
__device__ __forceinline__ float gelu_sig(float x){
    float e = __expf(-1.702f * x);
    return x * __builtin_amdgcn_rcpf(1.0f + e);
}
__device__ __forceinline__ float ldx(const void* p, size_t i, int f32){
    return f32 ? ((const float*)p)[i] : bf2f(((const __hip_bfloat16*)p)[i]);
}
__device__ __forceinline__ short f2bs(float x){
    __hip_bfloat16 h = __float2bfloat16(x);
    return *(short*)&h;
}
__device__ __forceinline__ float bs2f(unsigned short u){
    return __uint_as_float(((unsigned)u) << 16);
}
__device__ __forceinline__ bf16x8 ld8b(const void* p, size_t i, int f32){
    bf16x8 r;
    if (f32){
        const float4* f = (const float4*)((const float*)p + i);
        float4 a = f[0], b = f[1];
        r[0]=f2bs(a.x); r[1]=f2bs(a.y); r[2]=f2bs(a.z); r[3]=f2bs(a.w);
        r[4]=f2bs(b.x); r[5]=f2bs(b.y); r[6]=f2bs(b.z); r[7]=f2bs(b.w);
    } else {
        r = *(const bf16x8*)((const __hip_bfloat16*)p + i);
    }
    return r;
}
__device__ __forceinline__ float redsum16(float x){
    x += __shfl_xor(x, 1); x += __shfl_xor(x, 2);
    x += __shfl_xor(x, 4); x += __shfl_xor(x, 8);
    return x;
}
// detect f32 (1) vs bf16 (0) from bits 14..7 of first 64 words
__device__ __forceinline__ int detect_f32(const unsigned int* p){
    int inband = 0;
    #pragma unroll 1
    for (int w = 0; w < 64; ++w){
        unsigned int e0 = (p[w] >> 7) & 0xFFu;
        if (e0 >= 0x60u && e0 <= 0x8Eu) inband++;
    }
    return (inband >= 48) ? 0 : 1;
}
// ber_mask storage encoding: 0=u8, 1=i32, 2=bf16, 3=f32
__device__ __forceinline__ int ber_code(const unsigned char* r){
    bool has_big = false, odd1 = false, nz_off = false;
    #pragma unroll 1
    for (int j = 0; j < 128; ++j){
        unsigned char c = r[j];
        if (c > 1) has_big = true;
        if ((j & 3) == 1 && c) odd1 = true;
        if ((j & 3) != 0 && c) nz_off = true;
    }
    if (has_big) return odd1 ? 2 : 3;
    return nz_off ? 0 : 1;
}
__device__ __forceinline__ float ber_val(const unsigned char* r, int i, int code){
    switch (code){
        case 0:  return r[i] ? 1.f : 0.f;
        case 1:  return (((const int*)r)[i] != 0) ? 1.f : 0.f;
        case 2:  return (((const unsigned short*)r)[i] != 0) ? 1.f : 0.f;
        default: return (((const float*)r)[i] != 0.f) ? 1.f : 0.f;
    }
}

// ---------------------------------------------------------------------------
// kA: 3 independent roles, one launch (all inputs independent of each other):
//  blk<512:        depthwise conv+bias+residual -> qbf (PRE-BN bf16) + BN
//                  partial sums; blk 0 publishes dtype flag.
//  512<=blk<1024:  key-softmax partial denoms (max-free) + berf decode.
//  blk>=1024:      MFMA value projection -> vbT[bh][e][l].
// ---------------------------------------------------------------------------
__global__ __launch_bounds__(256, 2) void kA(const void* __restrict__ query,
                                             const void* __restrict__ conv_w,
                                             const void* __restrict__ conv_b,
                                             const void* __restrict__ keys,
                                             const void* __restrict__ values,
                                             const void* __restrict__ w_v,
                                             const unsigned char* __restrict__ ber_raw,
                                             float* __restrict__ statsP,
                                             float* __restrict__ Sp,
                                             float* __restrict__ berf,
                                             int* __restrict__ wsflag,
                                             __hip_bfloat16* __restrict__ qbf,
                                             __hip_bfloat16* __restrict__ vbT){
    __shared__ float tile[66][67];
    __shared__ float r1[256], r2[256];
    __shared__ float ss[4][64];
    __shared__ int sflag, sdet;
    int blk = blockIdx.x, t = threadIdx.x;
    if (blk < 512){
        // ---------------- conv role ----------------
        if (t == 0){
            sflag = detect_f32((const unsigned int*)query);
            if (blk == 0) wsflag[0] = sflag;
        }
        int lt = blk & 15, h = (blk >> 4) & 15, b = blk >> 8;
        int bh = b * HH + h;
        int l0 = lt * 64;
        if (t < 66){ tile[t][0] = 0.f; tile[t][65] = 0.f; }
        __syncthreads();
        const int f32 = sflag;
        for (int i = t; i < 66 * 64; i += 256){
            int r = i >> 6, d = i & 63;
            int l = l0 - 1 + r;
            tile[r][d + 1] = (l >= 0 && l < LL)
                           ? ldx(query, ((size_t)b * LL + l) * EE + h * 64 + d, f32) : 0.f;
        }
        __syncthreads();
        float w9[9];
        #pragma unroll
        for (int i = 0; i < 9; ++i) w9[i] = ldx(conv_w, h * 9 + i, f32);
        float cb = ldx(conv_b, h, f32);
        int l = t & 63, db = t >> 6, d0 = db * 16;
        float s1 = 0.f, s2 = 0.f;
        unsigned short ob[16];
        #pragma unroll
        for (int jj = 0; jj < 16; ++jj){
            int d = d0 + jj;
            float acc = cb + tile[l + 1][d + 1];
            #pragma unroll
            for (int di = 0; di < 3; ++di)
                #pragma unroll
                for (int dj = 0; dj < 3; ++dj)
                    acc += w9[di * 3 + dj] * tile[l + di][d + dj];
            s1 += acc; s2 += acc * acc;
            ob[jj] = (unsigned short)f2bs(acc);
        }
        __hip_bfloat16* orow = qbf + ((size_t)bh * LL + l0 + l) * DD + d0;
        #pragma unroll
        for (int g = 0; g < 4; ++g){
            ushort4 u; u.x = ob[g*4]; u.y = ob[g*4+1]; u.z = ob[g*4+2]; u.w = ob[g*4+3];
            *(ushort4*)(orow + g * 4) = u;
        }
        r1[t] = s1; r2[t] = s2;
        __syncthreads();
        for (int s = 128; s > 0; s >>= 1){
            if (t < s){ r1[t] += r1[t + s]; r2[t] += r2[t + s]; }
            __syncthreads();
        }
        if (t == 0){
            statsP[h * 32 + b * 16 + lt] = r1[0];
            statsP[512 + h * 32 + b * 16 + lt] = r2[0];
        }
    } else if (blk < 1024){
        // ---------------- key-softmax role ----------------
        int blk2 = blk - 512;
        if (t == 0){ sflag = detect_f32((const unsigned int*)keys); sdet = ber_code(ber_raw); }
        __syncthreads();
        const int f32 = sflag, code = sdet;
        int ch = blk2 & 15, h = (blk2 >> 4) & 15, b = blk2 >> 8;
        int ex = t & 63, ly = t >> 6;
        int e = h * 64 + ex;
        float s = 0.f;
        #pragma unroll 4
        for (int l = ch * 64 + ly; l < ch * 64 + 64; l += 4){
            float keep = ber_val(ber_raw, b * LL + l, code);
            float x = (keep != 0.f) ? ldx(keys, ((size_t)b * LL + l) * EE + e, f32) : NEGV;
            s += __expf(x);
        }
        ss[ly][ex] = s;
        __syncthreads();
        if (ly == 0)
            Sp[(b * 16 + ch) * EE + e] = ss[0][ex] + ss[1][ex] + ss[2][ex] + ss[3][ex];
        if (h == 0 && t < 64)
            berf[b * LL + ch * 64 + t] = ber_val(ber_raw, b * LL + ch * 64 + t, code);
    } else {
        // ---------------- MFMA v-projection role ----------------
        if (t == 0) sflag = detect_f32((const unsigned int*)values);
        __syncthreads();
        const int f32 = sflag;
        int blk2 = blk - 1024;
        int lt = blk2 & 15, bh = blk2 >> 4;
        int h = bh & 15, b = bh >> 4;
        int w = t >> 6, lane = t & 63;
        int lid = lane & 15, quad = lane >> 4;
        int l = lt * 64 + w * 16 + lid;
        bf16x8 av[2];
        #pragma unroll
        for (int ck = 0; ck < 2; ++ck)
            av[ck] = ld8b(values, ((size_t)b * LL + l) * EE + h * 64 + ck * 32 + quad * 8, f32);
        f32x4 Dv[4];
        #pragma unroll
        for (int et = 0; et < 4; ++et){
            Dv[et] = (f32x4){0.f, 0.f, 0.f, 0.f};
            #pragma unroll
            for (int ck = 0; ck < 2; ++ck){
                bf16x8 bw = ld8b(w_v, (size_t)(et * 16 + lid) * 64 + ck * 32 + quad * 8, f32);
                Dv[et] = __builtin_amdgcn_mfma_f32_16x16x32_bf16(av[ck], bw, Dv[et], 0, 0, 0);
            }
        }
        #pragma unroll
        for (int et = 0; et < 4; ++et){
            ushort4 u;
            u.x = (unsigned short)f2bs(Dv[et][0]);
            u.y = (unsigned short)f2bs(Dv[et][1]);
            u.z = (unsigned short)f2bs(Dv[et][2]);
            u.w = (unsigned short)f2bs(Dv[et][3]);
            *(ushort4*)(vbT + ((size_t)bh * DD + et * 16 + lid) * LL + lt * 64 + w * 16 + quad * 4) = u;
        }
    }
}

// ---------------------------------------------------------------------------
// kB: keys-build elementwise: kb = bf16(gelu(exp(keys)*Sinv)) with bernoulli
// mask (Sinv reduced locally from Sp). Block 0 also finalizes BN coefs.
// 1024 blocks x 256 thr, 8 elements/thread.
// ---------------------------------------------------------------------------
__global__ __launch_bounds__(256, 2) void kB(const void* __restrict__ keys,
                                             const void* __restrict__ bn_g,
                                             const void* __restrict__ bn_b,
                                             const float* __restrict__ statsP,
                                             const float* __restrict__ Sp,
                                             const float* __restrict__ berf,
                                             const int* __restrict__ wsflag,
                                             __hip_bfloat16* __restrict__ kb,
                                             float* __restrict__ coef){
    __shared__ float sinv_s[64];
    int blk = blockIdx.x, t = threadIdx.x;
    const int f32 = wsflag[0];
    if (blk == 0 && t < HH){
        int h = t;
        float s1 = 0.f, s2 = 0.f;
        #pragma unroll 1
        for (int j = 0; j < 32; ++j){
            s1 += statsP[h * 32 + j];
            s2 += statsP[512 + h * 32 + j];
        }
        const float N = (float)(BB * LL * DD);
        float mean = s1 / N;
        float var  = fmaxf(s2 / N - mean * mean, 0.f);
        float a = ldx(bn_g, h, f32) * rsqrtf(var + 1e-5f);
        coef[h] = a;
        coef[16 + h] = ldx(bn_b, h, f32) - mean * a;
    }
    int i8 = (blk * 256 + t) * 8;       // [b][h][l][d] over kb (2M els)
    int d0 = i8 & 63, l = (i8 >> 6) & 1023, h = (i8 >> 16) & 15, b = i8 >> 20;
    if (t < 64){
        int e = h * 64 + t;
        float S = 0.f;
        #pragma unroll
        for (int ch = 0; ch < 16; ++ch) S += Sp[(b * 16 + ch) * EE + e];
        sinv_s[t] = 1.f / S;
    }
    __syncthreads();
    size_t kbase = ((size_t)b * LL + l) * EE + h * 64 + d0;
    float kv[8];
    if (f32){
        const float4* kp = (const float4*)((const float*)keys + kbase);
        float4 a = kp[0], c = kp[1];
        kv[0]=a.x; kv[1]=a.y; kv[2]=a.z; kv[3]=a.w;
        kv[4]=c.x; kv[5]=c.y; kv[6]=c.z; kv[7]=c.w;
    } else {
        uint4 kr = *(const uint4*)((const __hip_bfloat16*)keys + kbase);
        unsigned short* ks = (unsigned short*)&kr;
        #pragma unroll
        for (int j = 0; j < 8; ++j) kv[j] = bs2f(ks[j]);
    }
    float keep = berf[b * LL + l];
    uint4 kw;
    unsigned short* kws = (unsigned short*)&kw;
    #pragma unroll
    for (int j = 0; j < 8; ++j){
        float km = (keep != 0.f) ? kv[j] : NEGV;
        float p = __expf(km) * sinv_s[d0 + j];
        kws[j] = (unsigned short)f2bs(gelu_erf(p));
    }
    *(uint4*)(kb + i8) = kw;
}

// ---------------------------------------------------------------------------
// kD: barrier-free MFMA flash attention + 1-deep K/V register prefetch,
// with BN+GELU of q fused on load (qbf is PRE-BN conv output).
// 2048 blocks x 128 thr (2 waves); block = (qt 16 q-rows, bh); waves split
// the k-range (cols w*32..w*32+31 of each 64-tile; additive max-free softmax).
// K/V fragments load DIRECTLY from global (L2-resident) -- no k-loop barriers.
// ---------------------------------------------------------------------------
__global__ __launch_bounds__(128, 4) void kD(const __hip_bfloat16* __restrict__ qbf,
                                             const __hip_bfloat16* __restrict__ kb,
                                             const __hip_bfloat16* __restrict__ vbT,
                                             const void* __restrict__ w_o,
                                             const void* __restrict__ b_o,
                                             const void* __restrict__ ln_g,
                                             const void* __restrict__ ln_b,
                                             const int* __restrict__ wsflag,
                                             const float* __restrict__ coef,
                                             void* __restrict__ out){
    __shared__ __align__(16) __hip_bfloat16 Pl[2][16][40];  // per-wave P (16x32)
    __shared__ __align__(16) float Ol[16][68];              // wave-1 O for combine
    __shared__ __align__(16) __hip_bfloat16 onb[16][72];    // LN'd rows (A-frags)
    int blk = blockIdx.x;
    int qt = 63 - (blk >> 5);         // 16-row q tile; LPT (heavy first)
    int bh = blk & 31;                // b*16+h ; same-bh blocks share an XCD
    int h = bh & 15, b = bh >> 4;
    int t = threadIdx.x;
    int w = t >> 6, lane = t & 63;
    int lid = lane & 15, quad = lane >> 4;
    const int f32o = wsflag[0];

    // Q A-frags: load pre-BN conv output, apply BN+GELU (fused; once per wave)
    int qrow = qt * 16 + lid;
    float bna = coef[h], bnc = coef[16 + h];
    bf16x8 qf[2];
    #pragma unroll
    for (int ck = 0; ck < 2; ++ck){
        bf16x8 raw = *(const bf16x8*)(qbf + ((size_t)bh * LL + qrow) * DD + ck * 32 + quad * 8);
        #pragma unroll
        for (int j = 0; j < 8; ++j)
            qf[ck][j] = f2bs(gelu_erf(bs2f((unsigned short)raw[j]) * bna + bnc));
    }

    const __hip_bfloat16* kbb = kb + (size_t)bh * LL * DD;
    const __hip_bfloat16* vbb = vbT + (size_t)bh * DD * LL;
    f32x4 O[4];
    #pragma unroll
    for (int nt = 0; nt < 4; ++nt) O[nt] = (f32x4){0.f, 0.f, 0.f, 0.f};
    const int qlane = qt * 16 + quad * 4;      // + r = this lane's q rows
    const int nkt = (qt >> 2) + 1;             // 64-k tiles covering causal range

    auto loadK = [&](int kw, bf16x8* dk){
        #pragma unroll
        for (int nt2 = 0; nt2 < 2; ++nt2)
            #pragma unroll
            for (int ck = 0; ck < 2; ++ck)
                dk[nt2 * 2 + ck] = *(const bf16x8*)(kbb
                    + (size_t)(kw + nt2 * 16 + lid) * DD + ck * 32 + quad * 8);
    };
    auto loadV = [&](int kw, bf16x8* dv){
        #pragma unroll
        for (int nt = 0; nt < 4; ++nt)
            dv[nt] = *(const bf16x8*)(vbb + (size_t)(nt * 16 + lid) * LL + kw + quad * 8);
    };

    bf16x8 kf[4], vf[4];
    loadK(w * 32, kf);
    loadV(w * 32, vf);

    for (int kt0 = 0; kt0 < nkt; ++kt0){
        bf16x8 kn[4], vn[4];
        const bool more = (kt0 + 1 < nkt);
        if (more){
            int kwn = (kt0 + 1) * 64 + w * 32;
            loadK(kwn, kn);
            loadV(kwn, vn);
        }
        int kw0 = kt0 * 64 + w * 32;
        // S = Q K^T for 16q x 32k (2 n-tiles)
        f32x4 S[2];
        #pragma unroll
        for (int nt2 = 0; nt2 < 2; ++nt2){
            S[nt2] = (f32x4){0.f, 0.f, 0.f, 0.f};
            #pragma unroll
            for (int ck = 0; ck < 2; ++ck)
                S[nt2] = __builtin_amdgcn_mfma_f32_16x16x32_bf16(qf[ck], kf[nt2 * 2 + ck], S[nt2], 0, 0, 0);
        }
        // p = exp(gelu(s)/32) causal-masked -> per-wave LDS (C -> A-frag layout)
        #pragma unroll
        for (int nt2 = 0; nt2 < 2; ++nt2){
            int kcol = kw0 + nt2 * 16 + lid;
            #pragma unroll
            for (int r = 0; r < 4; ++r){
                float x = gelu_sig(S[nt2][r]) * 0.03125f;
                float p = __expf(x);
                p = (kcol <= qlane + r) ? p : 0.f;
                Pl[w][quad * 4 + r][nt2 * 16 + lid] = __float2bfloat16(p);
            }
        }
        bf16x8 pa = *(const bf16x8*)&Pl[w][lid][quad * 8];   // same-wave RAW
        // O += P V
        #pragma unroll
        for (int nt = 0; nt < 4; ++nt)
            O[nt] = __builtin_amdgcn_mfma_f32_16x16x32_bf16(pa, vf[nt], O[nt], 0, 0, 0);
        if (more){
            #pragma unroll
            for (int i = 0; i < 4; ++i){ kf[i] = kn[i]; vf[i] = vn[i]; }
        }
    }

    // ---- combine the two k-half accumulators
    if (w == 1){
        #pragma unroll
        for (int nt = 0; nt < 4; ++nt)
            #pragma unroll
            for (int r = 0; r < 4; ++r)
                Ol[quad * 4 + r][nt * 16 + lid] = O[nt][r];
    }
    __syncthreads();
    if (w == 0){
        #pragma unroll
        for (int nt = 0; nt < 4; ++nt)
            #pragma unroll
            for (int r = 0; r < 4; ++r)
                O[nt][r] += Ol[quad * 4 + r][nt * 16 + lid];
        // LayerNorm over d (scale-invariant: unnormalized O is fine)
        float lng_v[4], lnb_v[4];
        #pragma unroll
        for (int nt = 0; nt < 4; ++nt){
            lng_v[nt] = ldx(ln_g, nt * 16 + lid, f32o);
            lnb_v[nt] = ldx(ln_b, nt * 16 + lid, f32o);
        }
        #pragma unroll
        for (int r = 0; r < 4; ++r){
            float s = O[0][r] + O[1][r] + O[2][r] + O[3][r];
            s = redsum16(s);
            float mu = s * (1.f / 64.f);
            float vs = 0.f;
            #pragma unroll
            for (int nt = 0; nt < 4; ++nt){ float d2 = O[nt][r] - mu; vs += d2 * d2; }
            vs = redsum16(vs);
            float iv = rsqrtf(vs * (1.f / 64.f) + 1e-5f);
            #pragma unroll
            for (int nt = 0; nt < 4; ++nt){
                float on = (O[nt][r] - mu) * iv * lng_v[nt] + lnb_v[nt];
                onb[quad * 4 + r][nt * 16 + lid] = __float2bfloat16(on);
            }
        }
    }
    __syncthreads();
    // ---- W_o epilogue, e-tiles split across waves (et = w*2 + i)
    bf16x8 oa0 = *(const bf16x8*)&onb[lid][quad * 8];
    bf16x8 oa1 = *(const bf16x8*)&onb[lid][32 + quad * 8];
    #pragma unroll
    for (int i = 0; i < 2; ++i){
        int et = w * 2 + i;
        float bo = ldx(b_o, et * 16 + lid, f32o);
        f32x4 R = (f32x4){bo, bo, bo, bo};
        bf16x8 bw0 = ld8b(w_o, (size_t)(et * 16 + lid) * 64 + quad * 8, f32o);
        bf16x8 bw1 = ld8b(w_o, (size_t)(et * 16 + lid) * 64 + 32 + quad * 8, f32o);
        R = __builtin_amdgcn_mfma_f32_16x16x32_bf16(oa0, bw0, R, 0, 0, 0);
        R = __builtin_amdgcn_mfma_f32_16x16x32_bf16(oa1, bw1, R, 0, 0, 0);
        #pragma unroll
        for (int r = 0; r < 4; ++r){
            size_t oidx = ((size_t)b * LL + qlane + r) * EE + h * 64 + et * 16 + lid;
            if (f32o) ((float*)out)[oidx] = R[r];
            else      ((__hip_bfloat16*)out)[oidx] = __float2bfloat16(R[r]);
        }
    }
}

// ---------------------------------------------------------------------------
extern "C" void kernel_launch(void* const* d_in, const int* in_sizes, int n_in,
                              void* d_out, int out_size, void* d_ws, size_t ws_size,
                              hipStream_t stream){
    int iq=-1, ik=-1, iv=-1, iber=-1, icw=-1, icb=-1, ibg=-1, ibb=-1,
        iwv=-1, ilg=-1, ilb=-1, iwo=-1, ibo=-1;
    int nbig=0, n16=0, n4096=0, n64=0;
    for (int i = 0; i < n_in; ++i){
        int s = in_sizes[i];
        if (s == BB*LL*EE){ if (nbig==0) iq=i; else if (nbig==1) ik=i; else if (nbig==2) iv=i; nbig++; }
        else if (s == BB*LL) iber = i;
        else if (s == HH*9)  icw = i;
        else if (s == HH){ if (n16==0) icb=i; else if (n16==1) ibg=i; else ibb=i; n16++; }
        else if (s == DD*DD){ if (n4096==0) iwv=i; else iwo=i; n4096++; }
        else if (s == DD){ if (n64==0) ilg=i; else if (n64==1) ilb=i; else ibo=i; n64++; }
    }
    if (iq<0||ik<0||iv<0||iber<0||icw<0||icb<0||ibg<0||ibb<0||iwv<0||ilg<0||ilb<0||iwo<0||ibo<0){
        iq=0; ik=1; iv=2; iber=5; icw=6; icb=7; ibg=8; ibb=9; iwv=10; ilg=11; ilb=12; iwo=13; ibo=14;
    }

    const size_t NEL = (size_t)BB * HH * LL * DD;   // 2M
    __hip_bfloat16* qbf = (__hip_bfloat16*)d_ws;    // 4 MB (pre-BN conv out)
    __hip_bfloat16* kbw = qbf + NEL;                // 4 MB
    __hip_bfloat16* vbT = kbw + NEL;                // 4 MB
    float* f     = (float*)(vbT + NEL);
    float* berf  = f;              // 2048
    float* statsP= f + 2048;       // 1024
    float* Sp    = f + 3072;       // 32768
    int*   wsflag= (int*)(f + 35840);  // 4
    float* coef  = f + 35856;      // 32

    hipLaunchKernelGGL(kA, dim3(1536), dim3(256), 0, stream,
                       d_in[iq], d_in[icw], d_in[icb], d_in[ik], d_in[iv], d_in[iwv],
                       (const unsigned char*)d_in[iber], statsP, Sp, berf, wsflag,
                       qbf, vbT);
    hipLaunchKernelGGL(kB, dim3(1024), dim3(256), 0, stream,
                       d_in[ik], d_in[ibg], d_in[ibb], statsP, Sp, berf, wsflag,
                       kbw, coef);
    hipLaunchKernelGGL(kD, dim3(2048), dim3(128), 0, stream,
                       qbf, kbw, vbT, d_in[iwo], d_in[ibo], d_in[ilg], d_in[ilb],
                       wsflag, coef, d_out);
}